// Round 12
// baseline (358.905 us; speedup 1.0000x reference)
//
#include <hip/hip_runtime.h>
#include <hip/hip_bf16.h>

// Problem constants
#define BATCH   4
#define SEQ     2048
#define DMODEL  1024
#define NHEADS  16
#define DHEAD   64
#define BT      (BATCH*SEQ)   // 8192 tokens

typedef unsigned short u16;
typedef unsigned int u32;
typedef __bf16 bf16x8 __attribute__((ext_vector_type(8)));
typedef float  f32x4  __attribute__((ext_vector_type(4)));
typedef float  f32x16 __attribute__((ext_vector_type(16)));
typedef u16    u16x8  __attribute__((ext_vector_type(8)));
typedef u16    u16x4  __attribute__((ext_vector_type(4)));
typedef u32    u32x4  __attribute__((ext_vector_type(4)));

#define MFMA32(a,b,c) __builtin_amdgcn_mfma_f32_32x32x16_bf16((a),(b),(c),0,0,0)

__device__ __forceinline__ u16 f2b(float f) {
  return __builtin_bit_cast(u16, (__bf16)f);
}
__device__ __forceinline__ u32 pack2(float lo, float hi) {
  return (u32)f2b(lo) | ((u32)f2b(hi) << 16);
}

__device__ __forceinline__ void gload_lds16(const u16* g, u16* l) {
  __builtin_amdgcn_global_load_lds(
      (const __attribute__((address_space(1))) void*)g,
      (__attribute__((address_space(3))) void*)l, 16, 0, 0);
}

// ---------------- elementwise f32 -> bf16 ----------------
__global__ __launch_bounds__(256) void cvt_bf16_kernel(
    const float* __restrict__ in, u16* __restrict__ out, int n8) {
  int i = blockIdx.x * 256 + threadIdx.x;
  if (i >= n8) return;
  const float4* p = (const float4*)(in + (long)i * 8);
  float4 a = p[0], b = p[1];
  u16x8 o;
  o[0]=f2b(a.x); o[1]=f2b(a.y); o[2]=f2b(a.z); o[3]=f2b(a.w);
  o[4]=f2b(b.x); o[5]=f2b(b.y); o[6]=f2b(b.z); o[7]=f2b(b.w);
  *(u16x8*)(out + (long)i * 8) = o;
}

// ---------------- transpose + cvt: W[K][N] f32 -> Wt[N][K] bf16 ----------------
__global__ __launch_bounds__(256) void transpose_cvt_kernel(
    const float* __restrict__ W, u16* __restrict__ Wt, int K, int N) {
  __shared__ float tile[32][33];   // +1 pad: no bank conflicts
  int tx = threadIdx.x & 31, ty = threadIdx.x >> 5; // 32x8
  int bx = blockIdx.x, by = blockIdx.y;
  #pragma unroll
  for (int r = 0; r < 32; r += 8)
    tile[ty + r][tx] = W[(long)(by * 32 + ty + r) * N + bx * 32 + tx];
  __syncthreads();
  #pragma unroll
  for (int r = 0; r < 32; r += 8)
    Wt[(long)(bx * 32 + ty + r) * K + by * 32 + tx] = f2b(tile[tx][ty + r]);
}

// ------- 128x(NBF*128) bf16 GEMM, B given transposed [N][K], 8 waves -------
// A staged in LDS (double-buffered, XOR-swizzled, gload_lds, counted vmcnt);
// B loaded DIRECT global->VGPR (L2-hot panel, compiler-scheduled waits).
// mfma_f32_32x32x16: wave (wm=w>>2, wn=w&3) owns 64 x (NBF*32) output.
// MODE 0: C[M][N] fp32 plain store.
// MODE 1: qkv scatter epilogue: col c = s*1024 + h*64 + d
//   s=0 -> Qb[bh][t][d] * 0.125   s=1 -> Kb[bh][t][d]   s=2 -> Vt[bh][d][t]
template<int MODE, int NBF>
__global__ __launch_bounds__(512, 2) void gemm_bt_kernel(
    const u16* __restrict__ A, const u16* __restrict__ Bt,
    float* __restrict__ C,
    u16* __restrict__ Qb, u16* __restrict__ Kb, u16* __restrict__ Vt,
    int M, int N, int K) {
  __shared__ u16 lA[2][128 * 64];   // [buf][row*64+col] bf16, rows 128B
  const int tid = threadIdx.x;
  const int lane = tid & 63, w = tid >> 6;
  const int c = lane & 31, g2 = lane >> 5;
  const int wm = w >> 2, wn = w & 3;
  const int bn = blockIdx.x, bm = blockIdx.y;
  // A staging: 2 gload_lds per tile, 512 thr x 16B; source pre-swizzled
  const int srow8 = tid >> 3, sslot = tid & 7;
  const int scol = (sslot ^ (srow8 & 7)) << 3;            // u16 units
  const u16* Ab = A + (long)(bm * 128 + srow8) * K + scol;
  const int ldst = srow8 * 64 + sslot * 8;                // u16 units
  // B direct-load base: rows bcol+nf*32, k-slice g2*8
  const int bcol = bn * (NBF * 128) + wn * (NBF * 32) + c;
  const u16* Bb = Bt + (long)bcol * K + g2 * 8;

  f32x16 acc[2][NBF];
  #pragma unroll
  for (int mf = 0; mf < 2; ++mf)
    #pragma unroll
    for (int nf = 0; nf < NBF; ++nf)
      #pragma unroll
      for (int e = 0; e < 16; ++e) acc[mf][nf][e] = 0.f;

  const int nt = K >> 6;
  // prologue: stage A tile 0
  gload_lds16(Ab, &lA[0][ldst]);
  gload_lds16(Ab + (long)64 * K, &lA[0][64 * 64 + ldst]);
  asm volatile("s_waitcnt vmcnt(0)" ::: "memory");
  __builtin_amdgcn_s_barrier();

  #pragma unroll 1
  for (int t = 0; t < nt; ++t) {
    const int cur = t & 1;
    // B fragments for tile t: NBF*4 x 16B global loads (L2-resident panel)
    bf16x8 bfrag[NBF][4];
    #pragma unroll
    for (int nf = 0; nf < NBF; ++nf)
      #pragma unroll
      for (int ks = 0; ks < 4; ++ks)
        bfrag[nf][ks] = *(const bf16x8*)(Bb + (long)nf * 32 * K + t * 64 + ks * 16);
    // stage A tile t+1; counted vmcnt keeps it in flight across barriers
    if (t + 1 < nt) {
      const long ko = (long)(t + 1) * 64;
      gload_lds16(Ab + ko, &lA[cur ^ 1][ldst]);
      gload_lds16(Ab + (long)64 * K + ko, &lA[cur ^ 1][64 * 64 + ldst]);
      if constexpr (NBF == 2) asm volatile("s_waitcnt vmcnt(10)" ::: "memory");
      else                    asm volatile("s_waitcnt vmcnt(6)" ::: "memory");
    } else {
      if constexpr (NBF == 2) asm volatile("s_waitcnt vmcnt(8)" ::: "memory");
      else                    asm volatile("s_waitcnt vmcnt(4)" ::: "memory");
    }
    __builtin_amdgcn_s_barrier();

    const char* a0 = (const char*)&lA[cur][0];
    const int swz = (c & 7) << 4;
    __builtin_amdgcn_s_setprio(1);
    #pragma unroll
    for (int ks = 0; ks < 4; ++ks) {
      bf16x8 af[2];
      #pragma unroll
      for (int mf = 0; mf < 2; ++mf)
        af[mf] = *(const bf16x8*)(a0 + (wm * 64 + mf * 32 + c) * 128 +
                                  ((ks * 32 + g2 * 16) ^ swz));
      #pragma unroll
      for (int mf = 0; mf < 2; ++mf)
        #pragma unroll
        for (int nf = 0; nf < NBF; ++nf)
          acc[mf][nf] = MFMA32(af[mf], bfrag[nf][ks], acc[mf][nf]);
    }
    __builtin_amdgcn_s_setprio(0);
    asm volatile("" ::: "memory");
    __builtin_amdgcn_s_barrier();
  }

  // epilogue: C/D map (32x32): col = lane&31, row = (r&3)+8*(r>>2)+4*g2
  #pragma unroll
  for (int mf = 0; mf < 2; ++mf) {
    #pragma unroll
    for (int nf = 0; nf < NBF; ++nf) {
      const int col = bn * (NBF * 128) + wn * (NBF * 32) + nf * 32 + c;
      #pragma unroll
      for (int r = 0; r < 16; ++r) {
        const int trow = bm * 128 + wm * 64 + mf * 32 + (r & 3) + 8 * (r >> 2) + 4 * g2;
        const float v = acc[mf][nf][r];
        if constexpr (MODE == 0) {
          C[(long)trow * N + col] = v;
        } else {
          const int s = col >> 10;
          const int rem = col & 1023;
          const int h = rem >> 6, d = rem & 63;
          const int b = trow >> 11, tt = trow & 2047;
          const int bh = b * NHEADS + h;
          if (s == 0)      Qb[((long)bh * SEQ + tt) * DHEAD + d] = f2b(v * 0.125f);
          else if (s == 1) Kb[((long)bh * SEQ + tt) * DHEAD + d] = f2b(v);
          else             Vt[((long)bh * DHEAD + d) * SEQ + tt] = f2b(v);
        }
      }
    }
  }
}

// ---------------- causal flash attention, 8-wave swapped-QK^T ----------------
// grid (64 bh, 4). Block (512 thr = 8 waves) processes q-blocks y*256 and
// (7-y)*256 -> constant 36 KV tiles of 64 keys. Wave w owns 32 q-rows.
// S^T = K*Q^T via mfma_32x32x16 so each lane holds 32 keys for ONE q
// (in-lane softmax + 1 shfl_xor(32)). K/V tiles cooperatively staged in LDS
// (double-buffered, XOR-swizzled source, counted vmcnt). P repacked to bf16
// B-operand in registers. Q pre-scaled by 1/8.
// K [bh][t][64], Vt [bh][64][t], out Ob [b*T+t][h*64+d] bf16.
__global__ __launch_bounds__(512, 2) void attn_kernel(
    const u16* __restrict__ Qb, const u16* __restrict__ Kb,
    const u16* __restrict__ Vt, u16* __restrict__ Ob) {
  __shared__ u16 kbuf[2][64 * 64];   // [key][d], rows 128B, XOR-swizzled
  __shared__ u16 vbuf[2][64 * 64];   // [d][key], rows 128B, XOR-swizzled
  const int tid = threadIdx.x;
  const int lane = tid & 63, w = tid >> 6;
  const int c = lane & 31, g2 = lane >> 5;
  const int bh = blockIdx.x;
  const int b = bh >> 4, h = bh & 15;
  const u16* Kbh = Kb + (long)bh * SEQ * DHEAD;
  const u16* Vbh = Vt + (long)bh * DHEAD * SEQ;

  // staging geometry: wave w stages rows w*8..w*8+7 of each tile (1KB issue)
  const int srow = lane >> 3;              // row within 8-row group
  const int sswz = ((lane & 7) * 16) ^ (srow << 4);   // bytes, pre-swizzled src
  const int swz  = (c & 7) << 4;           // read-side XOR (row&7 == c&7)

  #pragma unroll 1
  for (int pass = 0; pass < 2; ++pass) {
    const int qblk = pass ? (7 - (int)blockIdx.y) : (int)blockIdx.y;
    const int qb0 = qblk * 256;
    const int qrow0 = qb0 + w * 32;
    const int nt = qb0 / 64 + 4;           // tiles staged by the block
    const int mytiles = (qrow0 + 31) / 64 + 1;  // tiles this wave computes

    // Q fragments (B-operand): B[kk][j=c] = Q[qrow0+c][ds*16 + g2*8 + idx]
    bf16x8 qf[4];
    {
      const u16* Qrow = Qb + ((long)bh * SEQ + qrow0 + c) * DHEAD + g2 * 8;
      #pragma unroll
      for (int ds = 0; ds < 4; ++ds)
        qf[ds] = *(const bf16x8*)(Qrow + ds * 16);
    }

    f32x16 o0, o1;               // O^T accum: rows d (+0/+32), col q
    #pragma unroll
    for (int e = 0; e < 16; ++e) { o0[e] = 0.f; o1[e] = 0.f; }
    float m_run = -__builtin_inff(), l_run = 0.f;

    // prologue: stage tile 0
    {
      const u16* gk = Kbh + (long)(w * 8 + srow) * DHEAD + (sswz >> 1);
      gload_lds16(gk, &kbuf[0][w * 512]);
      const u16* gv = Vbh + (long)(w * 8 + srow) * SEQ + (sswz >> 1);
      gload_lds16(gv, &vbuf[0][w * 512]);
    }
    asm volatile("s_waitcnt vmcnt(0)" ::: "memory");
    __builtin_amdgcn_s_barrier();

    #pragma unroll 1
    for (int t = 0; t < nt; ++t) {
      const int kv = t * 64;
      const int cur = t & 1;
      if (t + 1 < nt) {
        const int kv2 = kv + 64;
        const u16* gk = Kbh + (long)(kv2 + w * 8 + srow) * DHEAD + (sswz >> 1);
        gload_lds16(gk, &kbuf[cur ^ 1][w * 512]);
        const u16* gv = Vbh + (long)(w * 8 + srow) * SEQ + kv2 + (sswz >> 1);
        gload_lds16(gv, &vbuf[cur ^ 1][w * 512]);
        asm volatile("s_waitcnt vmcnt(2)" ::: "memory");   // tile t complete
      } else {
        asm volatile("s_waitcnt vmcnt(0)" ::: "memory");
      }
      __builtin_amdgcn_s_barrier();

      if (t < mytiles) {
        // ---- S^T = K * Q^T : p0 keys kv..+31, p1 keys kv+32..+63 ----
        f32x16 p0, p1;
        #pragma unroll
        for (int e = 0; e < 16; ++e) { p0[e] = 0.f; p1[e] = 0.f; }
        const char* kb = (const char*)&kbuf[cur][0];
        __builtin_amdgcn_s_setprio(1);
        #pragma unroll
        for (int ds = 0; ds < 4; ++ds) {
          bf16x8 aK0 = *(const bf16x8*)(kb + c * 128 + ((ds * 32 + g2 * 16) ^ swz));
          bf16x8 aK1 = *(const bf16x8*)(kb + (32 + c) * 128 + ((ds * 32 + g2 * 16) ^ swz));
          p0 = MFMA32(aK0, qf[ds], p0);
          p1 = MFMA32(aK1, qf[ds], p1);
        }
        __builtin_amdgcn_s_setprio(0);

        // ---- causal mask: needed iff any key in tile can exceed the wave's
        // MIN q (qrow0). ----
        if (kv + 63 > qrow0) {
          const int q = qrow0 + c;
          #pragma unroll
          for (int r = 0; r < 16; ++r) {
            const int koff = (r & 3) + 8 * (r >> 2) + 4 * g2;
            if (kv + koff > q)      p0[r] = -__builtin_inff();
            if (kv + 32 + koff > q) p1[r] = -__builtin_inff();
          }
        }

        // ---- online softmax (in-lane over 32 keys + 1 half-swap) ----
        float vmax = p0[0];
        #pragma unroll
        for (int e = 1; e < 16; ++e) vmax = fmaxf(vmax, p0[e]);
        #pragma unroll
        for (int e = 0; e < 16; ++e) vmax = fmaxf(vmax, p1[e]);
        vmax = fmaxf(vmax, __shfl_xor(vmax, 32, 64));
        const float mnew = fmaxf(m_run, vmax);
        const float scale = __builtin_amdgcn_exp2f((m_run - mnew) * 1.44269504f);
        m_run = mnew;
        float ps = 0.f;
        #pragma unroll
        for (int e = 0; e < 16; ++e) {
          p0[e] = __builtin_amdgcn_exp2f((p0[e] - mnew) * 1.44269504f);
          p1[e] = __builtin_amdgcn_exp2f((p1[e] - mnew) * 1.44269504f);
          ps += p0[e] + p1[e];
        }
        ps += __shfl_xor(ps, 32, 64);
        l_run = l_run * scale + ps;
        #pragma unroll
        for (int e = 0; e < 16; ++e) { o0[e] *= scale; o1[e] *= scale; }

        // ---- repack P -> bf16 B-operand frags pbw[s] (16 keys each) ----
        u32x4 pbw[4];
        #pragma unroll
        for (int s = 0; s < 4; ++s) {
          const int base = 8 * (s & 1);
          float e0, e1, e2, e3, e4, e5, e6, e7;
          if (s < 2) {
            e0=p0[base+0]; e1=p0[base+1]; e2=p0[base+2]; e3=p0[base+3];
            e4=p0[base+4]; e5=p0[base+5]; e6=p0[base+6]; e7=p0[base+7];
          } else {
            e0=p1[base+0]; e1=p1[base+1]; e2=p1[base+2]; e3=p1[base+3];
            e4=p1[base+4]; e5=p1[base+5]; e6=p1[base+6]; e7=p1[base+7];
          }
          const u32 w01 = pack2(e0, e1), w23 = pack2(e2, e3);
          const u32 w45 = pack2(e4, e5), w67 = pack2(e6, e7);
          // send the words destined for the partner half, receive ours
          const u32 sendA = g2 ? w01 : w45;
          const u32 sendB = g2 ? w23 : w67;
          const u32 recvA = (u32)__shfl_xor((int)sendA, 32, 64);
          const u32 recvB = (u32)__shfl_xor((int)sendB, 32, 64);
          pbw[s][0] = g2 ? recvA : w01;
          pbw[s][1] = g2 ? recvB : w23;
          pbw[s][2] = g2 ? w45 : recvA;
          pbw[s][3] = g2 ? w67 : recvB;
        }

        // ---- O^T += V^T * P^T ----
        const char* vb = (const char*)&vbuf[cur][0];
        __builtin_amdgcn_s_setprio(1);
        #pragma unroll
        for (int s = 0; s < 4; ++s) {
          const bf16x8 pv = __builtin_bit_cast(bf16x8, pbw[s]);
          bf16x8 aV0 = *(const bf16x8*)(vb + c * 128 + ((s * 32 + g2 * 16) ^ swz));
          bf16x8 aV1 = *(const bf16x8*)(vb + (32 + c) * 128 + ((s * 32 + g2 * 16) ^ swz));
          o0 = MFMA32(aV0, pv, o0);
          o1 = MFMA32(aV1, pv, o1);
        }
        __builtin_amdgcn_s_setprio(0);
      }
      asm volatile("" ::: "memory");
      __builtin_amdgcn_s_barrier();
    }

    // ---- normalize + store [b*T+q][h*64 + d] ----
    const float rinv = 1.f / l_run;
    const int q = qrow0 + c;
    u16* orow = Ob + ((long)b * SEQ + q) * DMODEL + h * DHEAD;
    #pragma unroll
    for (int m = 0; m < 4; ++m) {
      u16x4 v0, v1;
      #pragma unroll
      for (int e = 0; e < 4; ++e) {
        v0[e] = f2b(o0[4 * m + e] * rinv);
        v1[e] = f2b(o1[4 * m + e] * rinv);
      }
      const int d0 = 8 * m + 4 * g2;
      *(u16x4*)(orow + d0) = v0;
      *(u16x4*)(orow + 32 + d0) = v1;
    }
  }
}

extern "C" void kernel_launch(void* const* d_in, const int* in_sizes, int n_in,
                              void* d_out, int out_size, void* d_ws, size_t ws_size,
                              hipStream_t stream) {
  const float* x    = (const float*)d_in[0];
  // d_in[1] = mask (causal tril) — implemented implicitly
  const float* Wqkv = (const float*)d_in[2];
  const float* Wout = (const float*)d_in[3];
  float* out = (float*)d_out;
  char* ws = (char*)d_ws;
  u16* Xb  = (u16*)(ws + 0);          // 8192x1024 bf16      16,777,216
  u16* Wt1 = (u16*)(ws + 16777216);   // 3072x1024 bf16       6,291,456
  u16* Wt2 = (u16*)(ws + 23068672);   // 1024x1024 bf16       2,097,152
  u16* Qb  = (u16*)(ws + 25165824);   // [64][2048][64] bf16 16,777,216
  u16* Kb  = (u16*)(ws + 41943040);   // [64][2048][64] bf16 16,777,216
  u16* Vt  = (u16*)(ws + 58720256);   // [64][64][2048] bf16 16,777,216
  u16* Ob  = (u16*)(ws + 75497472);   // 8192x1024 bf16      16,777,216

  cvt_bf16_kernel<<<4096, 256, 0, stream>>>(x, Xb, BT * DMODEL / 8);
  transpose_cvt_kernel<<<dim3(96, 32), 256, 0, stream>>>(Wqkv, Wt1, DMODEL, 3 * DMODEL);
  transpose_cvt_kernel<<<dim3(32, 32), 256, 0, stream>>>(Wout, Wt2, DMODEL, DMODEL);
  // G1: 128x256 tiles -> grid (3072/256, 8192/128) = (12, 64) = 768 = 3/CU
  gemm_bt_kernel<1, 2><<<dim3(12, 64), 512, 0, stream>>>(
      Xb, Wt1, nullptr, Qb, Kb, Vt, BT, 3 * DMODEL, DMODEL);
  attn_kernel<<<dim3(64, 4), 512, 0, stream>>>(Qb, Kb, Vt, Ob);
  // G2: 128x128 tiles -> grid (1024/128, 8192/128) = (8, 64) = 512 = 2/CU
  gemm_bt_kernel<0, 1><<<dim3(8, 64), 512, 0, stream>>>(
      Ob, Wt2, out, nullptr, nullptr, nullptr, BT, DMODEL, DMODEL);
}